// Round 8
// baseline (6820.723 us; speedup 1.0000x reference)
//
#include <hip/hip_runtime.h>
#include <math.h>

// ToxicityLSTM: 2-layer LSTM (B=64, T=1024, H=256, gates i,j,f,o, forget
// bias 1.0) + linear head (256->6) + sigmoid + threshold.
//
// Round 8 = R7 pipeline skeleton with the communication domain HALVED:
//   - 8 batch groups x 8 batches (was 4 x 16). Group = 32 blocks (16 L1 +
//     16 L2); block = 16 units x 8 batches (128 (b,u) pairs, same per-thread
//     work as R3/R7: W [4g][32k] in VGPRs, 512 FMA/step, 16-way k-combine).
//   - Coherent staging per block halves: panel [8 b][512 k]; high half =
//     8 KB, 2 loads/thread. Barrier scope halves: poll sweep = 32 flag
//     pairs (256 B dense).
//   - bgrp = blk & 7: XCD-affinity heuristic (perf-only; correctness never
//     depends on placement). If round-robin holds, each group's 16 L1
//     blocks share one XCD -> group's x slice fetched once per step.
//   - Deep pipeline (L2 @ t=s-2), LDS low-half prefetch during barrier
//     (BLOCKING loads only -- R6's in-flight-register UB is banned),
//     dense flags, finisher-direct flag store, poll on wave 3 (least busy).
//
// Slot map (R7-verified, re-derived for this geometry): h1 quad (slot t&3),
// h2 double (slot t&1). L1@s: low=x(s) [prefetched], high=h1(s-1) slot
// (s-1)&3, out h1(s) slot s&3. L2@s: low=h1(s-2) [prefetched at epilogue
// s-1: h1((s-1)-1... = h1(s-2)? no: epilogue of superstep s prefetches
// h1(s-1) for body s+1], high=h2(s-3) slot (s+1)&1, out h2(s-2) slot s&1.
// Anti-deps covered by barrier-per-superstep + slot distance (h1: 4, h2: 2).
// Head reads h2(1023) = slot (TT+1)&1 = 1.

#define BB 64
#define TT 1024
#define HH 256
#define NTHREADS 512
#define NGRPS 8
#define GB 8                             // batches per group
#define FLAG_BYTES 4096                  // 8 grp x 32 blk x 2 ints, dense
#define HBUF_FLOATS (BB * HH)            // 16384 floats per slot
#define WT_FLOATS (256 * 4 * 512)        // 524288 floats per layer
#define WS_NEEDED (FLAG_BYTES + (size_t)6 * HBUF_FLOATS * 4 + (size_t)2 * WT_FLOATS * 4)
#define HROW 576                         // skewed panel row stride (floats)

typedef float f32x4 __attribute__((ext_vector_type(4)));
typedef int   i32x2 __attribute__((ext_vector_type(2)));

__device__ __forceinline__ void coh_store(float* p, float v) {
  __hip_atomic_store(p, v, __ATOMIC_RELAXED, __HIP_MEMORY_SCOPE_AGENT);
}
__device__ __forceinline__ void coh_store_i(int* p, int v) {
  __hip_atomic_store(p, v, __ATOMIC_RELAXED, __HIP_MEMORY_SCOPE_AGENT);
}

// 2 device-coherent float4 loads in flight, one vmcnt drain (BLOCKING).
__device__ __forceinline__ void coh_load2(
    const float* p0, const float* p1, f32x4& a0, f32x4& a1) {
  asm volatile(
      "global_load_dwordx4 %0, %2, off sc0 sc1\n\t"
      "global_load_dwordx4 %1, %3, off sc0 sc1\n\t"
      "s_waitcnt vmcnt(0)"
      : "=&v"(a0), "=&v"(a1)
      : "v"(p0), "v"(p1)
      : "memory");
}

// One-time weight transpose: src [512 k][4 g * 256 u] -> dst [256 u][4 g][512 k]
__global__ void transpose_w(const float* __restrict__ src, float* __restrict__ dst) {
  __shared__ float t[64][65];
  const int g  = blockIdx.x;   // 4
  const int kt = blockIdx.y;   // 8 tiles over 512 k
  const int ut = blockIdx.z;   // 4 tiles over 256 u
  const int tx = threadIdx.x & 63;
  const int ty = threadIdx.x >> 6;
  #pragma unroll
  for (int r = ty; r < 64; r += 4)
    t[r][tx] = src[(size_t)(kt * 64 + r) * 1024 + g * 256 + ut * 64 + tx];
  __syncthreads();
  #pragma unroll
  for (int r = ty; r < 64; r += 4)
    dst[((size_t)(ut * 64 + r) * 4 + g) * 512 + kt * 64 + tx] = t[tx][r];
}

__global__ __launch_bounds__(NTHREADS, 2) void lstm2_persistent(
    const float* __restrict__ x,
    const float* __restrict__ b0, const float* __restrict__ b1,
    const float* __restrict__ wt0, const float* __restrict__ wt1,
    float* __restrict__ h1buf, float* __restrict__ h2buf,
    int* __restrict__ flags)
{
  __shared__ float hstage[GB * HROW];   // 18432 B operand panel (skewed)
  __shared__ f32x4 part[128 * 17];      // 34816 B k-partials (padded)

  const int blk   = blockIdx.x;
  const int bgrp  = blk & 7;                     // XCD-affinity interleave
  const int taskB = (blk >> 3) & 1;              // layer
  const int ublk  = blk >> 4;                    // 0..15 (16 units each)

  const int tid  = threadIdx.x;
  const int lane = tid & 63;
  const int ul   = tid & 15;                     // unit within block
  const int kq   = (tid >> 4) & 15;              // k-slice
  const int bt   = tid >> 8;                     // 0/1 (4 batch-rows each)
  const int cS   = tid & 127;                    // staging f4-col 0..127
  const int rS2  = (tid >> 7) * 2;               // staging rows rS2, rS2+1
  const int dposS = cS * 4 + (cS >> 3) * 4;      // skewed in-row position
  const bool evenW = (cS < 64);                  // wave-uniform: low half

  const float* WT   = taskB ? wt1 : wt0;
  const float* bias = taskB ? b1 : b0;

  // ---- loop-invariant weight slice into registers: [4 g][32 k] ----
  f32x4 w[4][8];
  {
    const float* wb = WT + (size_t)(ublk * 16 + ul) * 2048 + kq * 32;
    #pragma unroll
    for (int g = 0; g < 4; ++g)
      #pragma unroll
      for (int cc = 0; cc < 8; ++cc)
        w[g][cc] = *(const f32x4*)(wb + g * 512 + cc * 4);
  }

  // ---- finisher state (threads 0..127 own one (b,u): b=tid>>4, u=tid&15) ----
  float bi = 0.f, bj = 0.f, bfv = 0.f, bo = 0.f;
  if (tid < 128) {
    const int u = ublk * 16 + (tid & 15);
    bi  = bias[u];
    bj  = bias[256 + u];
    bfv = bias[512 + u];
    bo  = bias[768 + u];
  }
  float cst = 0.f;

  int* myflag = flags + ((size_t)bgrp * 32 + taskB * 16 + ublk) * 2;
  const size_t bxstep = (size_t)TT * HH;         // x batch-row stride

  // ---- prologue: L1 pre-stages x(0) low half (blocking, plain) ----
  if (!taskB && evenW) {
    const float* bx = x + ((size_t)(bgrp * GB + rS2) * TT + 0) * HH + cS * 4;
    f32x4 v0 = *(const f32x4*)(bx);
    f32x4 v1 = *(const f32x4*)(bx + bxstep);
    *(f32x4*)&hstage[(rS2 + 0) * HROW + dposS] = v0;
    *(f32x4*)&hstage[(rS2 + 1) * HROW + dposS] = v1;
  }

  // L1 processes t=s (active s<TT); L2 processes t=s-2 (active 2<=s<=TT+1).
  for (int s = 0; s <= TT + 1; ++s) {
    const bool active = taskB ? (s >= 2) : (s < TT);

    if (active) {
      // ---- stage HIGH panel half only (odd waves), post-barrier ----
      if (!evenW) {
        const float* src = taskB
            ? (h2buf + (size_t)((s + 1) & 1) * HBUF_FLOATS)   // h2(s-3)
            : (h1buf + (size_t)((s - 1) & 3) * HBUF_FLOATS);  // h1(s-1)
        const float* p0 = src + (size_t)(bgrp * GB + rS2) * HH + (cS & 63) * 4;
        f32x4 v0, v1;
        coh_load2(p0, p0 + HH, v0, v1);
        *(f32x4*)&hstage[(rS2 + 0) * HROW + dposS] = v0;
        *(f32x4*)&hstage[(rS2 + 1) * HROW + dposS] = v1;
      }
      __syncthreads();   // (A) panel complete (low half was pre-staged)

      // ---- gemv: 4 b x 4 g accumulators over 32-k slice ----
      float acc[4][4];
      #pragma unroll
      for (int b4 = 0; b4 < 4; ++b4)
        #pragma unroll
        for (int g = 0; g < 4; ++g) acc[b4][g] = 0.f;

      const int kbase = kq * 36;
      #pragma unroll
      for (int b4 = 0; b4 < 4; ++b4) {
        const float* hp = &hstage[(bt * 4 + b4) * HROW + kbase];
        #pragma unroll
        for (int cc = 0; cc < 8; ++cc) {
          const f32x4 h4 = *(const f32x4*)(hp + cc * 4);
          #pragma unroll
          for (int g = 0; g < 4; ++g) {
            acc[b4][g] = fmaf(h4[0], w[g][cc][0], acc[b4][g]);
            acc[b4][g] = fmaf(h4[1], w[g][cc][1], acc[b4][g]);
            acc[b4][g] = fmaf(h4[2], w[g][cc][2], acc[b4][g]);
            acc[b4][g] = fmaf(h4[3], w[g][cc][3], acc[b4][g]);
          }
        }
      }

      // ---- 16-way k-combine via padded LDS partials ----
      #pragma unroll
      for (int b4 = 0; b4 < 4; ++b4) {
        f32x4 p = { acc[b4][0], acc[b4][1], acc[b4][2], acc[b4][3] };
        part[((bt * 4 + b4) * 16 + ul) * 17 + kq] = p;
      }
      __syncthreads();   // (B) partials complete; hstage free for prefetch

      // ---- finish (waves 0-1): LSTM cell update, coherent h store ----
      if (tid < 128) {
        float gi = bi, gj = bj, gf = bfv, go = bo;
        #pragma unroll
        for (int q = 0; q < 16; ++q) {
          const f32x4 p = part[tid * 17 + q];
          gi += p[0]; gj += p[1]; gf += p[2]; go += p[3];
        }
        const float ig = 1.f / (1.f + expf(-gi));
        const float jt = tanhf(gj);
        const float fg = 1.f / (1.f + expf(-(gf + 1.0f)));
        const float og = 1.f / (1.f + expf(-go));
        cst = fg * cst + ig * jt;
        const float hn = og * tanhf(cst);

        float* hb = taskB
            ? (h2buf + (size_t)(s & 1) * HBUF_FLOATS)         // h2(s-2)
            : (h1buf + (size_t)(s & 3) * HBUF_FLOATS);        // h1(s)
        coh_store(hb + (size_t)(bgrp * GB + (tid >> 4)) * HH + ublk * 16 + (tid & 15), hn);
        asm volatile("s_waitcnt vmcnt(0)" ::: "memory");       // h before flag
      }
    }

    // ---- finisher-direct flag store (dense; also when inactive) ----
    if (s <= TT && tid < 128 && (tid & 63) == 0)
      coh_store_i(myflag + (tid >> 6), s + 1);

    // ---- prefetch NEXT body's low half into LDS (even waves, BLOCKING) ----
    if (evenW) {
      if (!taskB) {
        if (s + 1 < TT) {   // x(s+1)
          const float* bx = x + ((size_t)(bgrp * GB + rS2) * TT + (s + 1)) * HH + cS * 4;
          f32x4 v0 = *(const f32x4*)(bx);
          f32x4 v1 = *(const f32x4*)(bx + bxstep);
          *(f32x4*)&hstage[(rS2 + 0) * HROW + dposS] = v0;
          *(f32x4*)&hstage[(rS2 + 1) * HROW + dposS] = v1;
        }
      } else {
        if (s >= 1 && s <= TT) {  // h1(s-1) for body s+1, barrier(s-1)-confirmed
          const float* p0 = h1buf + (size_t)((s - 1) & 3) * HBUF_FLOATS
                          + (size_t)(bgrp * GB + rS2) * HH + cS * 4;
          f32x4 v0, v1;
          coh_load2(p0, p0 + HH, v0, v1);
          *(f32x4*)&hstage[(rS2 + 0) * HROW + dposS] = v0;
          *(f32x4*)&hstage[(rS2 + 1) * HROW + dposS] = v1;
        }
      }
    }

    // ---- lockstep barrier: wave 3 polls the group's 32 flag pairs ----
    if (s <= TT) {
      if (tid >= 192 && tid < 256) {
        const int* fp = flags + ((size_t)bgrp * 32 + (lane & 31)) * 2;
        for (;;) {
          i32x2 f;
          asm volatile(
              "global_load_dwordx2 %0, %1, off sc0 sc1\n\t"
              "s_waitcnt vmcnt(0)"
              : "=v"(f) : "v"(fp) : "memory");
          const int v = f[0] < f[1] ? f[0] : f[1];
          if (__all(v >= s + 1)) break;
          __builtin_amdgcn_s_sleep(1);
        }
      }
      __syncthreads();   // (C) barrier done; prefetched low half visible
    }
  }
}

// Head: logits = h2_last @ w_out + b_out; sigmoid; threshold.
__global__ void head_kernel(const float* __restrict__ h2last,
                            const float* __restrict__ w_out,
                            const float* __restrict__ b_out,
                            float* __restrict__ out)
{
  int tid = threadIdx.x;
  if (tid >= 384) return;
  int bb = tid / 6, cc = tid % 6;
  float acc = b_out[cc];
  const float* hr = h2last + bb * HH;
  #pragma unroll 4
  for (int uu = 0; uu < HH; ++uu) acc = fmaf(hr[uu], w_out[uu * 6 + cc], acc);
  out[tid] = acc;                            // logits
  float sg = 1.f / (1.f + expf(-acc));
  out[384 + tid] = sg;                       // sigmoid output
  out[768 + tid] = (sg > 0.5f) ? 1.f : 0.f;  // prediction
}

extern "C" void kernel_launch(void* const* d_in, const int* in_sizes, int n_in,
                              void* d_out, int out_size, void* d_ws, size_t ws_size,
                              hipStream_t stream) {
  const float* x     = (const float*)d_in[0];
  const float* k0    = (const float*)d_in[1];
  const float* b0    = (const float*)d_in[2];
  const float* k1    = (const float*)d_in[3];
  const float* b1    = (const float*)d_in[4];
  const float* w_out = (const float*)d_in[5];
  const float* b_out = (const float*)d_in[6];
  float* out = (float*)d_out;

  if (ws_size < WS_NEEDED) return;  // visible failure if ws too small

  int*   flags = (int*)d_ws;
  float* h1b   = (float*)((char*)d_ws + FLAG_BYTES);   // 4 slots (quad)
  float* h2b   = h1b + 4 * HBUF_FLOATS;                // 2 slots (double)
  float* wt0   = h2b + 2 * HBUF_FLOATS;
  float* wt1   = wt0 + WT_FLOATS;

  // Zero flags + all h slots (h(-1)=c(-1)=0): graph-replay deterministic.
  hipMemsetAsync(d_ws, 0, FLAG_BYTES + (size_t)6 * HBUF_FLOATS * 4, stream);

  transpose_w<<<dim3(4, 8, 4), 256, 0, stream>>>(k0, wt0);
  transpose_w<<<dim3(4, 8, 4), 256, 0, stream>>>(k1, wt1);

  lstm2_persistent<<<256, NTHREADS, 0, stream>>>(x, b0, b1, wt0, wt1,
                                                 h1b, h2b, flags);

  // h2(1023) lives in slot (TT+1)&1 = 1
  head_kernel<<<1, 384, 0, stream>>>(h2b + HBUF_FLOATS, w_out, b_out, out);
}

// Round 9
// 3990.959 us; speedup vs baseline: 1.7090x; 1.7090x over previous
//
#include <hip/hip_runtime.h>
#include <math.h>

// ToxicityLSTM: 2-layer LSTM (B=64, T=1024, H=256, gates i,j,f,o, forget
// bias 1.0) + linear head (256->6) + sigmoid + threshold.
//
// Round 9 = R7 base (4.14 ms; 256 blocks x 512 thr, 1 block/CU, W in VGPRs,
// skewed hstage, deep pipeline L2@t=s-2, dense flags) + three chain cuts:
//   1) WAVE-PRIVATE STAGING: wave w stages exactly the 4 panel rows its own
//      gemv reads (rows bt*4..bt*4+3; even waves low cols, odd waves high
//      cols). All staging->gemv LDS deps are same-wave program order ->
//      sync(A) deleted. Even waves enter gemv immediately post-barrier (low
//      half self-prefetched last epilogue); odd waves stage-then-compute.
//      Columns are disjoint (skew preserves low/high split), rows private
//      per wave -> race-free without the barrier. partials sync(B) is the
//      only intra-block rendezvous left besides the step barrier (C).
//   2) FAST GATES: sigmoid/tanh via v_exp_f32 + v_rcp_f32 (exp2f/rcpf
//      builtins; correct saturation at +-inf), replacing libm expf/tanhf in
//      the finish critical chain.
//   3) Poll loop without s_sleep (LLC load latency self-paces).
//
// Slot map (R7-verified): h1 quad (slot t&3), h2 double (slot t&1).
// L1@s: low=x(s) [self-prefetched], high=h1(s-1) slot (s-1)&3, out h1(s)
// slot s&3. L2@s: low=h1(s-2) [self-prefetched at epilogue s-1], high=
// h2(s-3) slot (s+1)&1, out h2(s-2) slot s&1. Head reads h2(1023) slot 1.

#define BB 64
#define TT 1024
#define HH 256
#define NTHREADS 512
#define FLAG_BYTES 4096                  // 4 bgrp x 64 blk x 2 ints, dense
#define HBUF_FLOATS (BB * HH)            // 16384 floats per slot
#define WT_FLOATS (256 * 4 * 512)        // 524288 floats per layer
#define WS_NEEDED (FLAG_BYTES + (size_t)6 * HBUF_FLOATS * 4 + (size_t)2 * WT_FLOATS * 4)
#define HROW 576                         // skewed panel row stride (floats)

typedef float f32x4 __attribute__((ext_vector_type(4)));
typedef int   i32x2 __attribute__((ext_vector_type(2)));

__device__ __forceinline__ void coh_store(float* p, float v) {
  __hip_atomic_store(p, v, __ATOMIC_RELAXED, __HIP_MEMORY_SCOPE_AGENT);
}
__device__ __forceinline__ void coh_store_i(int* p, int v) {
  __hip_atomic_store(p, v, __ATOMIC_RELAXED, __HIP_MEMORY_SCOPE_AGENT);
}

// 4 device-coherent float4 loads in flight, one vmcnt drain (BLOCKING).
__device__ __forceinline__ void coh_load4(
    const float* p0, const float* p1, const float* p2, const float* p3,
    f32x4& a0, f32x4& a1, f32x4& a2, f32x4& a3) {
  asm volatile(
      "global_load_dwordx4 %0, %4, off sc0 sc1\n\t"
      "global_load_dwordx4 %1, %5, off sc0 sc1\n\t"
      "global_load_dwordx4 %2, %6, off sc0 sc1\n\t"
      "global_load_dwordx4 %3, %7, off sc0 sc1\n\t"
      "s_waitcnt vmcnt(0)"
      : "=&v"(a0), "=&v"(a1), "=&v"(a2), "=&v"(a3)
      : "v"(p0), "v"(p1), "v"(p2), "v"(p3)
      : "memory");
}

// Fast sigmoid/tanh on v_exp_f32 + v_rcp_f32. Saturation: exp2(+inf)=inf ->
// rcp=0; exp2(-large)=0 -> exact 0/1 tails. ~1ulp core accuracy.
__device__ __forceinline__ float fsig(float x) {
  const float e = __builtin_amdgcn_exp2f(x * -1.442695040888963f);  // e^-x
  return __builtin_amdgcn_rcpf(1.0f + e);
}
__device__ __forceinline__ float ftanh(float x) {
  const float e = __builtin_amdgcn_exp2f(x * 2.885390081777927f);   // e^(2x)
  return 1.0f - 2.0f * __builtin_amdgcn_rcpf(e + 1.0f);
}

// One-time weight transpose: src [512 k][4 g * 256 u] -> dst [256 u][4 g][512 k]
__global__ void transpose_w(const float* __restrict__ src, float* __restrict__ dst) {
  __shared__ float t[64][65];
  const int g  = blockIdx.x;   // 4
  const int kt = blockIdx.y;   // 8 tiles over 512 k
  const int ut = blockIdx.z;   // 4 tiles over 256 u
  const int tx = threadIdx.x & 63;
  const int ty = threadIdx.x >> 6;
  #pragma unroll
  for (int r = ty; r < 64; r += 4)
    t[r][tx] = src[(size_t)(kt * 64 + r) * 1024 + g * 256 + ut * 64 + tx];
  __syncthreads();
  #pragma unroll
  for (int r = ty; r < 64; r += 4)
    dst[((size_t)(ut * 64 + r) * 4 + g) * 512 + kt * 64 + tx] = t[tx][r];
}

__global__ __launch_bounds__(NTHREADS, 2) void lstm2_persistent(
    const float* __restrict__ x,
    const float* __restrict__ b0, const float* __restrict__ b1,
    const float* __restrict__ wt0, const float* __restrict__ wt1,
    float* __restrict__ h1buf, float* __restrict__ h2buf,
    int* __restrict__ flags)
{
  __shared__ float hstage[16 * HROW];   // 36864 B operand panel (skewed)
  __shared__ f32x4 part[128 * 17];      // 34816 B k-partials (padded)

  const int blk   = blockIdx.x;
  const int taskB = blk >= 128;                  // layer2 blocks
  const int tblk  = taskB ? blk - 128 : blk;
  const int bgrp  = tblk >> 5;                   // 4 groups of 16 b
  const int ublk  = tblk & 31;                   // 32 groups of 8 u

  const int tid  = threadIdx.x;
  const int lane = tid & 63;
  const int wv   = tid >> 6;
  const int ul   = tid & 7;
  const int kq   = (tid >> 3) & 15;              // even waves: 0-7, odd: 8-15
  const int bt   = tid >> 7;
  const bool odd = wv & 1;                       // high-half (k 256..511) wave
  const int r0S  = (wv >> 1) * 4;                // == bt*4: my gemv rows
  const int cS   = lane + (odd ? 64 : 0);        // staging f4-col
  const int dposS = cS * 4 + (cS >> 3) * 4;      // skewed in-row position

  const float* WT   = taskB ? wt1 : wt0;
  const float* bias = taskB ? b1 : b0;

  // ---- loop-invariant weight slice into registers: [4 g][32 k] ----
  f32x4 w[4][8];
  {
    const float* wb = WT + (size_t)(ublk * 8 + ul) * 2048 + kq * 32;
    #pragma unroll
    for (int g = 0; g < 4; ++g)
      #pragma unroll
      for (int cc = 0; cc < 8; ++cc)
        w[g][cc] = *(const f32x4*)(wb + g * 512 + cc * 4);
  }

  // ---- finisher state (threads 0..127 own one (b,u)) ----
  float bi = 0.f, bj = 0.f, bfv = 0.f, bo = 0.f;
  if (tid < 128) {
    const int u = ublk * 8 + (tid & 7);
    bi  = bias[u];
    bj  = bias[256 + u];
    bfv = bias[512 + u];
    bo  = bias[768 + u];
  }
  float cst = 0.f;

  int* myflag = flags + ((size_t)bgrp * 64 + (taskB ? 32 : 0) + ublk) * 2;

  // ---- prologue: L1 even waves self-stage x(0) rows r0S..r0S+3 ----
  if (!taskB && !odd) {
    const float* bx = x + ((size_t)(bgrp * 16 + r0S) * TT + 0) * HH + lane * 4;
    const size_t rstep = (size_t)TT * HH;
    f32x4 v0 = *(const f32x4*)(bx);
    f32x4 v1 = *(const f32x4*)(bx + rstep);
    f32x4 v2 = *(const f32x4*)(bx + 2 * rstep);
    f32x4 v3 = *(const f32x4*)(bx + 3 * rstep);
    *(f32x4*)&hstage[(r0S + 0) * HROW + dposS] = v0;
    *(f32x4*)&hstage[(r0S + 1) * HROW + dposS] = v1;
    *(f32x4*)&hstage[(r0S + 2) * HROW + dposS] = v2;
    *(f32x4*)&hstage[(r0S + 3) * HROW + dposS] = v3;
  }

  // L1 processes t=s (active s<TT); L2 processes t=s-2 (active 2<=s<=TT+1).
  for (int s = 0; s <= TT + 1; ++s) {
    const bool active = taskB ? (s >= 2) : (s < TT);

    if (active) {
      // ---- odd waves: stage OWN high rows (blocking), then compute ----
      if (odd) {
        const float* src = taskB
            ? (h2buf + (size_t)((s + 1) & 1) * HBUF_FLOATS)   // h2(s-3)
            : (h1buf + (size_t)((s - 1) & 3) * HBUF_FLOATS);  // h1(s-1)
        const float* p0 = src + (size_t)(bgrp * 16 + r0S) * HH + lane * 4;
        f32x4 v0, v1, v2, v3;
        coh_load4(p0, p0 + HH, p0 + 2 * HH, p0 + 3 * HH, v0, v1, v2, v3);
        *(f32x4*)&hstage[(r0S + 0) * HROW + dposS] = v0;
        *(f32x4*)&hstage[(r0S + 1) * HROW + dposS] = v1;
        *(f32x4*)&hstage[(r0S + 2) * HROW + dposS] = v2;
        *(f32x4*)&hstage[(r0S + 3) * HROW + dposS] = v3;
      }
      // (no sync: every wave reads only rows it staged itself)

      // ---- gemv: 4 b x 4 g accumulators over 32-k slice ----
      float acc[4][4];
      #pragma unroll
      for (int b4 = 0; b4 < 4; ++b4)
        #pragma unroll
        for (int g = 0; g < 4; ++g) acc[b4][g] = 0.f;

      const int kbase = kq * 36;
      #pragma unroll
      for (int b4 = 0; b4 < 4; ++b4) {
        const float* hp = &hstage[(bt * 4 + b4) * HROW + kbase];
        #pragma unroll
        for (int cc = 0; cc < 8; ++cc) {
          const f32x4 h4 = *(const f32x4*)(hp + cc * 4);
          #pragma unroll
          for (int g = 0; g < 4; ++g) {
            acc[b4][g] = fmaf(h4[0], w[g][cc][0], acc[b4][g]);
            acc[b4][g] = fmaf(h4[1], w[g][cc][1], acc[b4][g]);
            acc[b4][g] = fmaf(h4[2], w[g][cc][2], acc[b4][g]);
            acc[b4][g] = fmaf(h4[3], w[g][cc][3], acc[b4][g]);
          }
        }
      }

      // ---- 16-way k-combine via padded LDS partials ----
      #pragma unroll
      for (int b4 = 0; b4 < 4; ++b4) {
        f32x4 p = { acc[b4][0], acc[b4][1], acc[b4][2], acc[b4][3] };
        part[((bt * 4 + b4) * 8 + ul) * 17 + kq] = p;
      }
      __syncthreads();   // (B) partials complete; hstage reads done block-wide

      // ---- finish (waves 0-1): LSTM cell update, coherent h store ----
      if (tid < 128) {
        float gi = bi, gj = bj, gf = bfv, go = bo;
        #pragma unroll
        for (int q = 0; q < 16; ++q) {
          const f32x4 p = part[tid * 17 + q];
          gi += p[0]; gj += p[1]; gf += p[2]; go += p[3];
        }
        const float ig = fsig(gi);
        const float jt = ftanh(gj);
        const float fg = fsig(gf + 1.0f);
        const float og = fsig(go);
        cst = fg * cst + ig * jt;
        const float hn = og * ftanh(cst);

        float* hb = taskB
            ? (h2buf + (size_t)(s & 1) * HBUF_FLOATS)         // h2(s-2)
            : (h1buf + (size_t)(s & 3) * HBUF_FLOATS);        // h1(s)
        coh_store(hb + (size_t)(bgrp * 16 + (tid >> 3)) * HH + ublk * 8 + (tid & 7), hn);
        asm volatile("s_waitcnt vmcnt(0)" ::: "memory");       // h before flag
      }
    }

    // ---- finisher-direct flag store (dense; also when inactive) ----
    if (s <= TT && tid < 128 && (tid & 63) == 0)
      coh_store_i(myflag + (tid >> 6), s + 1);

    // ---- even waves: self-prefetch NEXT body's low rows (BLOCKING) ----
    // Ordered after this step's gemv reads by syncthreads(B).
    if (!odd) {
      if (!taskB) {
        if (s + 1 < TT) {   // x(s+1)
          const float* bx = x + ((size_t)(bgrp * 16 + r0S) * TT + (s + 1)) * HH + lane * 4;
          const size_t rstep = (size_t)TT * HH;
          f32x4 v0 = *(const f32x4*)(bx);
          f32x4 v1 = *(const f32x4*)(bx + rstep);
          f32x4 v2 = *(const f32x4*)(bx + 2 * rstep);
          f32x4 v3 = *(const f32x4*)(bx + 3 * rstep);
          *(f32x4*)&hstage[(r0S + 0) * HROW + dposS] = v0;
          *(f32x4*)&hstage[(r0S + 1) * HROW + dposS] = v1;
          *(f32x4*)&hstage[(r0S + 2) * HROW + dposS] = v2;
          *(f32x4*)&hstage[(r0S + 3) * HROW + dposS] = v3;
        }
      } else {
        if (s >= 1 && s <= TT) {  // h1(s-1) for body s+1, barrier(s-1)-confirmed
          const float* p0 = h1buf + (size_t)((s - 1) & 3) * HBUF_FLOATS
                          + (size_t)(bgrp * 16 + r0S) * HH + lane * 4;
          f32x4 v0, v1, v2, v3;
          coh_load4(p0, p0 + HH, p0 + 2 * HH, p0 + 3 * HH, v0, v1, v2, v3);
          *(f32x4*)&hstage[(r0S + 0) * HROW + dposS] = v0;
          *(f32x4*)&hstage[(r0S + 1) * HROW + dposS] = v1;
          *(f32x4*)&hstage[(r0S + 2) * HROW + dposS] = v2;
          *(f32x4*)&hstage[(r0S + 3) * HROW + dposS] = v3;
        }
      }
    }

    // ---- lockstep barrier: wave 0 polls 64 blocks' dense flag pairs ----
    if (s <= TT) {
      if (tid < 64) {
        const int* fp = flags + ((size_t)bgrp * 64 + tid) * 2;
        for (;;) {
          i32x2 f;
          asm volatile(
              "global_load_dwordx2 %0, %1, off sc0 sc1\n\t"
              "s_waitcnt vmcnt(0)"
              : "=v"(f) : "v"(fp) : "memory");
          const int v = f[0] < f[1] ? f[0] : f[1];
          if (__all(v >= s + 1)) break;
        }
      }
      __syncthreads();   // (C) step framing; prefetched low half visible
    }
  }
}

// Head: logits = h2_last @ w_out + b_out; sigmoid; threshold.
__global__ void head_kernel(const float* __restrict__ h2last,
                            const float* __restrict__ w_out,
                            const float* __restrict__ b_out,
                            float* __restrict__ out)
{
  int tid = threadIdx.x;
  if (tid >= 384) return;
  int bb = tid / 6, cc = tid % 6;
  float acc = b_out[cc];
  const float* hr = h2last + bb * HH;
  #pragma unroll 4
  for (int uu = 0; uu < HH; ++uu) acc = fmaf(hr[uu], w_out[uu * 6 + cc], acc);
  out[tid] = acc;                            // logits
  float sg = 1.f / (1.f + expf(-acc));
  out[384 + tid] = sg;                       // sigmoid output
  out[768 + tid] = (sg > 0.5f) ? 1.f : 0.f;  // prediction
}

extern "C" void kernel_launch(void* const* d_in, const int* in_sizes, int n_in,
                              void* d_out, int out_size, void* d_ws, size_t ws_size,
                              hipStream_t stream) {
  const float* x     = (const float*)d_in[0];
  const float* k0    = (const float*)d_in[1];
  const float* b0    = (const float*)d_in[2];
  const float* k1    = (const float*)d_in[3];
  const float* b1    = (const float*)d_in[4];
  const float* w_out = (const float*)d_in[5];
  const float* b_out = (const float*)d_in[6];
  float* out = (float*)d_out;

  if (ws_size < WS_NEEDED) return;  // visible failure if ws too small

  int*   flags = (int*)d_ws;
  float* h1b   = (float*)((char*)d_ws + FLAG_BYTES);   // 4 slots (quad)
  float* h2b   = h1b + 4 * HBUF_FLOATS;                // 2 slots (double)
  float* wt0   = h2b + 2 * HBUF_FLOATS;
  float* wt1   = wt0 + WT_FLOATS;

  // Zero flags + all h slots (h(-1)=c(-1)=0): graph-replay deterministic.
  hipMemsetAsync(d_ws, 0, FLAG_BYTES + (size_t)6 * HBUF_FLOATS * 4, stream);

  transpose_w<<<dim3(4, 8, 4), 256, 0, stream>>>(k0, wt0);
  transpose_w<<<dim3(4, 8, 4), 256, 0, stream>>>(k1, wt1);

  lstm2_persistent<<<256, NTHREADS, 0, stream>>>(x, b0, b1, wt0, wt1,
                                                 h1b, h2b, flags);

  // h2(1023) lives in slot 1023&1 = 1
  head_kernel<<<1, 384, 0, stream>>>(h2b + HBUF_FLOATS, w_out, b_out, out);
}